// Round 1
// baseline (642.925 us; speedup 1.0000x reference)
//
#include <hip/hip_runtime.h>
#include <hip/hip_bf16.h>

// Hierarchical softmax skip-gram scorer.
// out[b] = prod_l sigmoid(sign[b,l] * dot(logistic[path_idx[b,l]], encoder[v_j[b]]))
// with masked (padded) levels contributing 1.0. mask == (sign != 0), padding trailing.
//
// v1: one wave (64 lanes) per batch element; float2 per lane covers D=128.
// Coalesced 512 B row loads, butterfly shuffle reduce, uniform control flow.

#define D 128

__global__ __launch_bounds__(256) void hs_prob_kernel(
    const float* __restrict__ encoder,
    const float* __restrict__ logistic,
    const int*   __restrict__ v_j,
    const int*   __restrict__ path_idx,
    const int*   __restrict__ path_sign,
    float*       __restrict__ out,
    int B, int L)
{
    const int gtid = blockIdx.x * blockDim.x + threadIdx.x;
    const int wave = gtid >> 6;       // one wave per batch element
    const int lane = threadIdx.x & 63;
    if (wave >= B) return;
    const int b = wave;

    // h = encoder[v_j[b]]  — 512 B coalesced row load, 2 floats per lane
    const int vj = v_j[b];                     // wave-uniform (scalar load)
    const float2 h = ((const float2*)(encoder + (long long)vj * D))[lane];

    const int* idxp = path_idx  + (long long)b * L;
    const int* sgnp = path_sign + (long long)b * L;

    float prod = 1.0f;
    for (int l = 0; l < L; ++l) {
        const int sgn = sgnp[l];               // wave-uniform
        if (sgn == 0) break;                   // trailing padding
        const int idx = idxp[l];               // wave-uniform
        const float2 w = ((const float2*)(logistic + (long long)idx * D))[lane];

        float part = fmaf(w.x, h.x, w.y * h.y);
        // butterfly reduce across all 64 lanes
        #pragma unroll
        for (int off = 32; off; off >>= 1)
            part += __shfl_xor(part, off, 64);

        const float x = (float)sgn * part;     // signed logit
        prod *= 1.0f / (1.0f + expf(-x));      // sigmoid, all lanes redundantly
    }

    if (lane == 0) out[b] = prod;
}

extern "C" void kernel_launch(void* const* d_in, const int* in_sizes, int n_in,
                              void* d_out, int out_size, void* d_ws, size_t ws_size,
                              hipStream_t stream) {
    const float* encoder   = (const float*)d_in[0];
    const float* logistic  = (const float*)d_in[1];
    const int*   v_j       = (const int*)d_in[2];
    const int*   path_idx  = (const int*)d_in[3];
    const int*   path_sign = (const int*)d_in[4];
    // d_in[5] = path_mask (bool) — unused: mask == (path_sign != 0)

    const int B = in_sizes[2];
    const int L = in_sizes[3] / B;

    float* out = (float*)d_out;

    const int block = 256;                     // 4 waves per block
    const int grid  = (B * 64 + block - 1) / block;
    hipLaunchKernelGGL(hs_prob_kernel, dim3(grid), dim3(block), 0, stream,
                       encoder, logistic, v_j, path_idx, path_sign, out, B, L);
}

// Round 2
// 630.455 us; speedup vs baseline: 1.0198x; 1.0198x over previous
//
#include <hip/hip_runtime.h>
#include <hip/hip_bf16.h>

// Hierarchical softmax skip-gram scorer.
// out[b] = prod_l sigmoid(sign[b,l] * dot(logistic[path_idx[b,l]], encoder[v_j[b]]))
// padded levels (sign==0) contribute 1.0. mask == (sign != 0).
//
// v2: one wave per batch element; chunk-of-4 level processing for 4x
// memory-level parallelism (v1 serialized ~19 dependent load round-trips).
// No early break — padding handled by select, so loads pipeline freely.

#define D 128

__device__ __forceinline__ float wave_reduce64(float v) {
    #pragma unroll
    for (int off = 32; off; off >>= 1)
        v += __shfl_xor(v, off, 64);
    return v;
}

__global__ __launch_bounds__(256) void hs_prob_kernel(
    const float* __restrict__ encoder,
    const float* __restrict__ logistic,
    const int*   __restrict__ v_j,
    const int*   __restrict__ path_idx,
    const int*   __restrict__ path_sign,
    float*       __restrict__ out,
    int B, int L)
{
    const int gtid = blockIdx.x * blockDim.x + threadIdx.x;
    const int wave = gtid >> 6;       // one wave per batch element
    const int lane = threadIdx.x & 63;
    if (wave >= B) return;
    const int b = wave;

    // h = encoder[v_j[b]] — 512 B coalesced row load, 2 floats per lane
    const int vj = v_j[b];                     // wave-uniform
    const float2 h = ((const float2*)(encoder + (long long)vj * D))[lane];

    const int* idxp = path_idx  + (long long)b * L;
    const int* sgnp = path_sign + (long long)b * L;

    float prod = 1.0f;

    int l = 0;
    for (; l + 4 <= L; l += 4) {
        // 4 independent index/sign loads (wave-uniform addresses)
        int ix0 = idxp[l],     ix1 = idxp[l + 1], ix2 = idxp[l + 2], ix3 = idxp[l + 3];
        int sg0 = sgnp[l],     sg1 = sgnp[l + 1], sg2 = sgnp[l + 2], sg3 = sgnp[l + 3];

        // 4 independent 512 B row loads — all in flight together.
        // Padded levels have ix==0: row 0 is valid, result discarded by select.
        const float2 w0 = ((const float2*)(logistic + (long long)ix0 * D))[lane];
        const float2 w1 = ((const float2*)(logistic + (long long)ix1 * D))[lane];
        const float2 w2 = ((const float2*)(logistic + (long long)ix2 * D))[lane];
        const float2 w3 = ((const float2*)(logistic + (long long)ix3 * D))[lane];

        float p0 = fmaf(w0.x, h.x, w0.y * h.y);
        float p1 = fmaf(w1.x, h.x, w1.y * h.y);
        float p2 = fmaf(w2.x, h.x, w2.y * h.y);
        float p3 = fmaf(w3.x, h.x, w3.y * h.y);

        // 4 interleaved butterflies — shuffle stages independent across p0..p3
        #pragma unroll
        for (int off = 32; off; off >>= 1) {
            p0 += __shfl_xor(p0, off, 64);
            p1 += __shfl_xor(p1, off, 64);
            p2 += __shfl_xor(p2, off, 64);
            p3 += __shfl_xor(p3, off, 64);
        }

        float s0 = 1.0f / (1.0f + expf(-(float)sg0 * p0));
        float s1 = 1.0f / (1.0f + expf(-(float)sg1 * p1));
        float s2 = 1.0f / (1.0f + expf(-(float)sg2 * p2));
        float s3 = 1.0f / (1.0f + expf(-(float)sg3 * p3));

        prod *= (sg0 ? s0 : 1.0f);
        prod *= (sg1 ? s1 : 1.0f);
        prod *= (sg2 ? s2 : 1.0f);
        prod *= (sg3 ? s3 : 1.0f);
    }

    for (; l < L; ++l) {                       // tail (L % 4 levels)
        int ix = idxp[l];
        int sg = sgnp[l];
        const float2 w = ((const float2*)(logistic + (long long)ix * D))[lane];
        float p = fmaf(w.x, h.x, w.y * h.y);
        p = wave_reduce64(p);
        float s = 1.0f / (1.0f + expf(-(float)sg * p));
        prod *= (sg ? s : 1.0f);
    }

    if (lane == 0) out[b] = prod;
}

extern "C" void kernel_launch(void* const* d_in, const int* in_sizes, int n_in,
                              void* d_out, int out_size, void* d_ws, size_t ws_size,
                              hipStream_t stream) {
    const float* encoder   = (const float*)d_in[0];
    const float* logistic  = (const float*)d_in[1];
    const int*   v_j       = (const int*)d_in[2];
    const int*   path_idx  = (const int*)d_in[3];
    const int*   path_sign = (const int*)d_in[4];
    // d_in[5] = path_mask (bool) — unused: mask == (path_sign != 0)

    const int B = in_sizes[2];
    const int L = in_sizes[3] / B;

    float* out = (float*)d_out;

    const int block = 256;                     // 4 waves per block
    const int grid  = (B * 64 + block - 1) / block;
    hipLaunchKernelGGL(hs_prob_kernel, dim3(grid), dim3(block), 0, stream,
                       encoder, logistic, v_j, path_idx, path_sign, out, B, L);
}

// Round 3
// 624.991 us; speedup vs baseline: 1.0287x; 1.0087x over previous
//
#include <hip/hip_runtime.h>
#include <hip/hip_bf16.h>

// Hierarchical softmax skip-gram scorer.
// out[b] = prod_l sigmoid(sign[b,l] * dot(logistic[path_idx[b,l]], encoder[v_j[b]]))
// padded levels (sign==0) contribute 1.0. mask == (sign != 0).
//
// v3: one wave per batch element, HALF-WAVE split — lanes 0-31 handle even
// levels, 32-63 odd levels (float4 x 32 lanes = one 512 B row each). One
// instruction stream retires 2 levels at once: 5-stage butterfly instead of
// 2x6, one __expf for two levels. Metadata (idx,sign) preloaded lane-parallel
// packed as c = sign*idx (c==0 <=> padding; real idx >= 2), recovered with one
// ds_bpermute per slot. 4 slots (8 levels) in flight for MLP.

#define D 128

__global__ __launch_bounds__(256) void hs_prob_kernel(
    const float* __restrict__ encoder,
    const float* __restrict__ logistic,
    const int*   __restrict__ v_j,
    const int*   __restrict__ path_idx,
    const int*   __restrict__ path_sign,
    float*       __restrict__ out,
    int B, int L)
{
    const int gtid = blockIdx.x * blockDim.x + threadIdx.x;
    const int wave = gtid >> 6;       // one wave per batch element
    const int lane = threadIdx.x & 63;
    if (wave >= B) return;
    const int b = wave;

    const int half    = lane >> 5;    // 0 = even levels, 1 = odd levels
    const int sublane = lane & 31;

    // h = encoder[v_j[b]] — float4 per lane, both halves read the same row
    const int vj = v_j[b];                     // wave-uniform
    const float4 h = ((const float4*)(encoder + (long long)vj * D))[sublane];

    // Lane-parallel metadata preload: c = sign * idx. c==0 <=> padded level.
    int c_l = 0;
    if (lane < L)
        c_l = path_sign[(long long)b * L + lane] * path_idx[(long long)b * L + lane];

    const int S = (L + 2) >> 1;       // slots; slot s covers levels 2s+half
    float prod = 1.0f;                // per-half partial product

    int s = 0;
    for (; s + 4 <= S; s += 4) {
        // recover (idx,sign) for this half's 4 levels — one bpermute each
        const int c0 = __shfl(c_l, 2*(s+0) + half, 64);
        const int c1 = __shfl(c_l, 2*(s+1) + half, 64);
        const int c2 = __shfl(c_l, 2*(s+2) + half, 64);
        const int c3 = __shfl(c_l, 2*(s+3) + half, 64);

        const int ix0 = c0 < 0 ? -c0 : c0;
        const int ix1 = c1 < 0 ? -c1 : c1;
        const int ix2 = c2 < 0 ? -c2 : c2;
        const int ix3 = c3 < 0 ? -c3 : c3;

        // 4 independent row loads per half (8 levels in flight per wave)
        const float4 w0 = ((const float4*)(logistic + (long long)ix0 * D))[sublane];
        const float4 w1 = ((const float4*)(logistic + (long long)ix1 * D))[sublane];
        const float4 w2 = ((const float4*)(logistic + (long long)ix2 * D))[sublane];
        const float4 w3 = ((const float4*)(logistic + (long long)ix3 * D))[sublane];

        float p0 = fmaf(w0.x, h.x, fmaf(w0.y, h.y, fmaf(w0.z, h.z, w0.w * h.w)));
        float p1 = fmaf(w1.x, h.x, fmaf(w1.y, h.y, fmaf(w1.z, h.z, w1.w * h.w)));
        float p2 = fmaf(w2.x, h.x, fmaf(w2.y, h.y, fmaf(w2.z, h.z, w2.w * h.w)));
        float p3 = fmaf(w3.x, h.x, fmaf(w3.y, h.y, fmaf(w3.z, h.z, w3.w * h.w)));

        // 5-stage butterfly within each 32-lane half (offsets < 32 stay in-half)
        #pragma unroll
        for (int off = 16; off; off >>= 1) {
            p0 += __shfl_xor(p0, off, 64);
            p1 += __shfl_xor(p1, off, 64);
            p2 += __shfl_xor(p2, off, 64);
            p3 += __shfl_xor(p3, off, 64);
        }

        const float x0 = c0 > 0 ? p0 : -p0;
        const float x1 = c1 > 0 ? p1 : -p1;
        const float x2 = c2 > 0 ? p2 : -p2;
        const float x3 = c3 > 0 ? p3 : -p3;

        const float f0 = 1.0f / (1.0f + __expf(-x0));
        const float f1 = 1.0f / (1.0f + __expf(-x1));
        const float f2 = 1.0f / (1.0f + __expf(-x2));
        const float f3 = 1.0f / (1.0f + __expf(-x3));

        prod *= (c0 ? f0 : 1.0f);
        prod *= (c1 ? f1 : 1.0f);
        prod *= (c2 ? f2 : 1.0f);
        prod *= (c3 ? f3 : 1.0f);
    }

    for (; s < S; ++s) {              // tail slots
        const int c = __shfl(c_l, 2*s + half, 64);
        const int ix = c < 0 ? -c : c;
        const float4 w = ((const float4*)(logistic + (long long)ix * D))[sublane];
        float p = fmaf(w.x, h.x, fmaf(w.y, h.y, fmaf(w.z, h.z, w.w * h.w)));
        #pragma unroll
        for (int off = 16; off; off >>= 1)
            p += __shfl_xor(p, off, 64);
        const float x = c > 0 ? p : -p;
        const float f = 1.0f / (1.0f + __expf(-x));
        prod *= (c ? f : 1.0f);
    }

    // combine the two halves' partial products
    prod *= __shfl_xor(prod, 32, 64);

    if (lane == 0) out[b] = prod;
}

extern "C" void kernel_launch(void* const* d_in, const int* in_sizes, int n_in,
                              void* d_out, int out_size, void* d_ws, size_t ws_size,
                              hipStream_t stream) {
    const float* encoder   = (const float*)d_in[0];
    const float* logistic  = (const float*)d_in[1];
    const int*   v_j       = (const int*)d_in[2];
    const int*   path_idx  = (const int*)d_in[3];
    const int*   path_sign = (const int*)d_in[4];
    // d_in[5] = path_mask (bool) — unused: mask == (path_sign != 0)

    const int B = in_sizes[2];
    const int L = in_sizes[3] / B;

    float* out = (float*)d_out;

    const int block = 256;                     // 4 waves per block
    const int grid  = (B * 64 + block - 1) / block;
    hipLaunchKernelGGL(hs_prob_kernel, dim3(grid), dim3(block), 0, stream,
                       encoder, logistic, v_j, path_idx, path_sign, out, B, L);
}